// Round 1
// baseline (265.504 us; speedup 1.0000x reference)
//
#include <hip/hip_runtime.h>
#include <math.h>

// Fused 3-layer MLP: h1 = relu(x@W1^T+b1) [B,3]; h2 = relu(h1@W2^T+b2) [B,2];
// out = sigmoid(h2@W3^T+b3) [B].  All fp32.  Memory-bound: 32 B/row traffic.
// 4 rows per thread -> all global accesses are aligned float4.

__global__ __launch_bounds__(256) void mlp321_kernel(
    const float* __restrict__ x,
    const float* __restrict__ W1, const float* __restrict__ b1,
    const float* __restrict__ W2, const float* __restrict__ b2,
    const float* __restrict__ W3, const float* __restrict__ b3,
    float* __restrict__ out_p, float* __restrict__ h1_p, float* __restrict__ h2_p,
    int nrows)
{
    const int t = blockIdx.x * blockDim.x + threadIdx.x;
    const int row0 = t * 4;
    if (row0 >= nrows) return;

    // Weights: tiny, uniform address -> cache broadcast.
    float w1[6], w2[6], w3v[2], bb1[3], bb2[2], bb3;
#pragma unroll
    for (int i = 0; i < 6; ++i) w1[i] = W1[i];
#pragma unroll
    for (int i = 0; i < 3; ++i) bb1[i] = b1[i];
#pragma unroll
    for (int i = 0; i < 6; ++i) w2[i] = W2[i];
#pragma unroll
    for (int i = 0; i < 2; ++i) bb2[i] = b2[i];
    w3v[0] = W3[0]; w3v[1] = W3[1];
    bb3 = b3[0];

    // Load 4 rows of x (8 floats) as two float4.
    const float4* xv = reinterpret_cast<const float4*>(x + (size_t)row0 * 2);
    float4 xa = xv[0];
    float4 xb = xv[1];
    float xr[4][2] = {{xa.x, xa.y}, {xa.z, xa.w}, {xb.x, xb.y}, {xb.z, xb.w}};

    float h1v[4][3], h2v[4][2], ov[4];
#pragma unroll
    for (int r = 0; r < 4; ++r) {
        const float x0 = xr[r][0], x1 = xr[r][1];
#pragma unroll
        for (int j = 0; j < 3; ++j) {
            float v = fmaf(x0, w1[j * 2 + 0], fmaf(x1, w1[j * 2 + 1], bb1[j]));
            h1v[r][j] = v > 0.f ? v : 0.f;
        }
#pragma unroll
        for (int k = 0; k < 2; ++k) {
            float v = bb2[k];
#pragma unroll
            for (int j = 0; j < 3; ++j) v = fmaf(h1v[r][j], w2[k * 3 + j], v);
            h2v[r][k] = v > 0.f ? v : 0.f;
        }
        float z = fmaf(h2v[r][0], w3v[0], fmaf(h2v[r][1], w3v[1], bb3));
        ov[r] = 1.f / (1.f + __expf(-z));
    }

    // out: 1 float4
    reinterpret_cast<float4*>(out_p + row0)[0] = make_float4(ov[0], ov[1], ov[2], ov[3]);

    // h1: 12 floats -> 3 float4 (base 3*row0 is multiple of 12 -> 16B aligned)
    float4* h1v4 = reinterpret_cast<float4*>(h1_p + (size_t)row0 * 3);
    h1v4[0] = make_float4(h1v[0][0], h1v[0][1], h1v[0][2], h1v[1][0]);
    h1v4[1] = make_float4(h1v[1][1], h1v[1][2], h1v[2][0], h1v[2][1]);
    h1v4[2] = make_float4(h1v[2][2], h1v[3][0], h1v[3][1], h1v[3][2]);

    // h2: 8 floats -> 2 float4
    float4* h2v4 = reinterpret_cast<float4*>(h2_p + (size_t)row0 * 2);
    h2v4[0] = make_float4(h2v[0][0], h2v[0][1], h2v[1][0], h2v[1][1]);
    h2v4[1] = make_float4(h2v[2][0], h2v[2][1], h2v[3][0], h2v[3][1]);
}

extern "C" void kernel_launch(void* const* d_in, const int* in_sizes, int n_in,
                              void* d_out, int out_size, void* d_ws, size_t ws_size,
                              hipStream_t stream) {
    const float* x  = (const float*)d_in[0];
    const float* W1 = (const float*)d_in[1];
    const float* b1 = (const float*)d_in[2];
    const float* W2 = (const float*)d_in[3];
    const float* b2 = (const float*)d_in[4];
    const float* W3 = (const float*)d_in[5];
    const float* b3 = (const float*)d_in[6];

    const int B = in_sizes[0] / 2;  // x is [B, 2]
    float* out_p = (float*)d_out;          // [B]
    float* h1_p  = out_p + (size_t)B;      // [B,3]
    float* h2_p  = h1_p + (size_t)B * 3;   // [B,2]

    const int threads = 256;
    const int rows_per_thread = 4;
    const int blocks = (B + threads * rows_per_thread - 1) / (threads * rows_per_thread);
    mlp321_kernel<<<blocks, threads, 0, stream>>>(x, W1, b1, W2, b2, W3, b3,
                                                  out_p, h1_p, h2_p, B);
}

// Round 3
// 257.077 us; speedup vs baseline: 1.0328x; 1.0328x over previous
//
#include <hip/hip_runtime.h>
#include <math.h>

// Fused 3-layer MLP: h1 = relu(x@W1^T+b1) [B,3]; h2 = relu(h1@W2^T+b2) [B,2];
// out = sigmoid(h2@W3^T+b3) [B].  All fp32.  Memory-bound: 32 B/row traffic
// (8 B read + 24 B write), 256 MiB total at B=8.39M -> ~43 us floor @6.3 TB/s.
//
// R1/R2: stage outputs in LDS per 1024-row block, then drain with fully
// lane-contiguous float4 non-temporal stores. R0's direct stores were
// lane-strided (48 B / 32 B stride), costing ~3x cache-line transactions.
// R2 fix: __builtin_nontemporal_store needs a native vector type, not
// HIP_vector_type<float,4> -> use ext_vector_type(4).

#define RPB 1024  // rows per block (256 threads x 4 rows)

typedef float v4f __attribute__((ext_vector_type(4)));

__global__ __launch_bounds__(256) void mlp321_kernel(
    const float* __restrict__ x,
    const float* __restrict__ W1, const float* __restrict__ b1,
    const float* __restrict__ W2, const float* __restrict__ b2,
    const float* __restrict__ W3, const float* __restrict__ b3,
    float* __restrict__ out_p, float* __restrict__ h1_p, float* __restrict__ h2_p,
    int nrows)
{
    __shared__ __align__(16) float s_h1[RPB * 3];  // 12 KB
    __shared__ __align__(16) float s_h2[RPB * 2];  //  8 KB
    __shared__ __align__(16) float s_out[RPB];     //  4 KB

    const int tid = threadIdx.x;
    const size_t base = (size_t)blockIdx.x * RPB;

    // Weights: tiny, uniform -> scalar loads / cache broadcast.
    float w1[6], w2[6], w3v[2], bb1[3], bb2[2], bb3;
#pragma unroll
    for (int i = 0; i < 6; ++i) w1[i] = W1[i];
#pragma unroll
    for (int i = 0; i < 3; ++i) bb1[i] = b1[i];
#pragma unroll
    for (int i = 0; i < 6; ++i) w2[i] = W2[i];
#pragma unroll
    for (int i = 0; i < 2; ++i) bb2[i] = b2[i];
    w3v[0] = W3[0]; w3v[1] = W3[1];
    bb3 = b3[0];

    const bool full = (base + RPB) <= (size_t)nrows;

    // ---- compute phase: lane-contiguous float4 x-loads (2 rows each) ----
    const v4f* xv = reinterpret_cast<const v4f*>(x + base * 2);  // 512 v4f
#pragma unroll
    for (int it = 0; it < 2; ++it) {
        const int idx = it * 256 + tid;        // float4 index within chunk
        const int r0 = idx * 2;                // first of 2 rows
        if (!full && (base + r0) >= (size_t)nrows) continue;
        v4f xa = xv[idx];
        float xr[2][2] = {{xa.x, xa.y}, {xa.z, xa.w}};
#pragma unroll
        for (int r = 0; r < 2; ++r) {
            const int row = r0 + r;
            if (!full && (base + row) >= (size_t)nrows) continue;
            const float x0 = xr[r][0], x1 = xr[r][1];
            float h1v[3];
#pragma unroll
            for (int j = 0; j < 3; ++j) {
                float v = fmaf(x0, w1[j * 2 + 0], fmaf(x1, w1[j * 2 + 1], bb1[j]));
                h1v[j] = v > 0.f ? v : 0.f;
                s_h1[row * 3 + j] = h1v[j];
            }
            float h2v[2];
#pragma unroll
            for (int k = 0; k < 2; ++k) {
                float v = bb2[k];
#pragma unroll
                for (int j = 0; j < 3; ++j) v = fmaf(h1v[j], w2[k * 3 + j], v);
                h2v[k] = v > 0.f ? v : 0.f;
                s_h2[row * 2 + k] = h2v[k];
            }
            float z = fmaf(h2v[0], w3v[0], fmaf(h2v[1], w3v[1], bb3));
            s_out[row] = 1.f / (1.f + __expf(-z));
        }
    }
    __syncthreads();

    // ---- drain phase: fully coalesced float4 non-temporal stores ----
    if (full) {
        const v4f* so = reinterpret_cast<const v4f*>(s_out);
        const v4f* s1 = reinterpret_cast<const v4f*>(s_h1);
        const v4f* s2 = reinterpret_cast<const v4f*>(s_h2);
        v4f* po = reinterpret_cast<v4f*>(out_p + base);       // 256 v4f
        v4f* p1 = reinterpret_cast<v4f*>(h1_p + base * 3);    // 768 v4f
        v4f* p2 = reinterpret_cast<v4f*>(h2_p + base * 2);    // 512 v4f

        __builtin_nontemporal_store(so[tid], po + tid);
#pragma unroll
        for (int it = 0; it < 3; ++it) {
            const int i = it * 256 + tid;
            __builtin_nontemporal_store(s1[i], p1 + i);
        }
#pragma unroll
        for (int it = 0; it < 2; ++it) {
            const int i = it * 256 + tid;
            __builtin_nontemporal_store(s2[i], p2 + i);
        }
    } else {
        // tail block: scalar guarded stores
        const int remain = (int)((size_t)nrows - base);
        for (int r = tid; r < remain; r += 256) {
            out_p[base + r] = s_out[r];
            h1_p[(base + r) * 3 + 0] = s_h1[r * 3 + 0];
            h1_p[(base + r) * 3 + 1] = s_h1[r * 3 + 1];
            h1_p[(base + r) * 3 + 2] = s_h1[r * 3 + 2];
            h2_p[(base + r) * 2 + 0] = s_h2[r * 2 + 0];
            h2_p[(base + r) * 2 + 1] = s_h2[r * 2 + 1];
        }
    }
}

extern "C" void kernel_launch(void* const* d_in, const int* in_sizes, int n_in,
                              void* d_out, int out_size, void* d_ws, size_t ws_size,
                              hipStream_t stream) {
    const float* x  = (const float*)d_in[0];
    const float* W1 = (const float*)d_in[1];
    const float* b1 = (const float*)d_in[2];
    const float* W2 = (const float*)d_in[3];
    const float* b2 = (const float*)d_in[4];
    const float* W3 = (const float*)d_in[5];
    const float* b3 = (const float*)d_in[6];

    const int B = in_sizes[0] / 2;  // x is [B, 2]
    float* out_p = (float*)d_out;          // [B]
    float* h1_p  = out_p + (size_t)B;      // [B,3]
    float* h2_p  = h1_p + (size_t)B * 3;   // [B,2]

    const int blocks = (B + RPB - 1) / RPB;
    mlp321_kernel<<<blocks, 256, 0, stream>>>(x, W1, b1, W2, b2, W3, b3,
                                              out_p, h1_p, h2_p, B);
}